// Round 7
// baseline (438.388 us; speedup 1.0000x reference)
//
#include <hip/hip_runtime.h>
#include <hip/hip_cooperative_groups.h>
#include <math.h>

namespace cg = cooperative_groups;

#define NROWS 8192
#define KDIM  768
#define BM 128
#define BN 128
#define BK 64
#define KTILES (KDIM / BK)   // 12
#define NBC 4                // bc tiles swept per block
#define NBCG (NROWS / BN / NBC)  // 16 column groups -> grid 64*16 = 1024 = 4/CU

typedef short bf16x8 __attribute__((ext_vector_type(8)));  // 8 bf16 = 4 VGPRs
typedef float f32x4  __attribute__((ext_vector_type(4)));

static __device__ __forceinline__ unsigned short f2bf_rne(float f) {
    unsigned x = __float_as_uint(f);
    unsigned r = x + 0x7fffu + ((x >> 16) & 1u);   // round-to-nearest-even
    return (unsigned short)(r >> 16);
}
// monotonic float<->uint encoding so atomicMax(uint) == float max
static __device__ __forceinline__ unsigned enc_f(float f) {
    unsigned x = __float_as_uint(f);
    return (x & 0x80000000u) ? ~x : (x | 0x80000000u);
}
static __device__ __forceinline__ float dec_f(unsigned u) {
    unsigned x = (u & 0x80000000u) ? (u ^ 0x80000000u) : ~u;
    return __uint_as_float(x);
}

// ---------------- fused cooperative kernel: normalize -> gemm+rowmax -> decode
__global__ __launch_bounds__(256, 4) void fused_k(
        const float* __restrict__ ex, const float* __restrict__ ey,
        unsigned short* __restrict__ ws, unsigned* __restrict__ out) {
    cg::grid_group grid = cg::this_grid();
    const int tid  = threadIdx.x;
    const int wave = tid >> 6, lane = tid & 63;

    // ===== phase 1: out-init + normalize (4096 waves x 4 rows, wave-per-row)
    {
        const int gtid = blockIdx.x * 256 + tid;
        if (gtid < NROWS) out[gtid] = enc_f(-INFINITY);
        const int wid = gtid >> 6;               // 0..4095
        #pragma unroll 1
        for (int rr = 0; rr < 4; ++rr) {
            const int grow = wid + rr * 4096;    // 0..16383, each row once
            const float* src = (grow < NROWS) ? ex : ey;
            const int row = grow & (NROWS - 1);
            const float4* xr = (const float4*)(src + (size_t)row * KDIM);
            float4 v[3];
            #pragma unroll
            for (int g = 0; g < 3; ++g) v[g] = xr[lane + g * 64];
            float ss = 0.f;
            #pragma unroll
            for (int g = 0; g < 3; ++g)
                ss += v[g].x * v[g].x + v[g].y * v[g].y + v[g].z * v[g].z + v[g].w * v[g].w;
            #pragma unroll
            for (int off = 32; off > 0; off >>= 1) ss += __shfl_xor(ss, off);
            const float scale = 1.0f / fmaxf(sqrtf(ss), 1e-8f);
            ushort4* dr = (ushort4*)(ws + (size_t)grow * KDIM);
            #pragma unroll
            for (int g = 0; g < 3; ++g) {
                ushort4 o;
                o.x = f2bf_rne(v[g].x * scale); o.y = f2bf_rne(v[g].y * scale);
                o.z = f2bf_rne(v[g].z * scale); o.w = f2bf_rne(v[g].w * scale);
                dr[lane + g * 64] = o;
            }
        }
    }
    grid.sync();

    // ===== phase 2: persistent-strip GEMM + row-max (R6 core, 852 TF proven)
    {
        const unsigned short* A = ws;                            // exn
        const unsigned short* B = ws + (size_t)NROWS * KDIM;     // eyn
        __shared__ unsigned short As[BM * BK];   // 16 KB
        __shared__ unsigned short Bs[BN * BK];   // 16 KB

        const int br  = blockIdx.x >> 4;         // 0..63
        const int bcg = blockIdx.x & 15;         // 0..15

        // staging: slot s of row r holds global 16B-chunk g = s ^ (r&7)
        const int srow   = lane >> 3;
        const int gchunk = (lane & 7) ^ srow;
        const int scol   = gchunk * 8;           // shorts
        const unsigned short* aStage = A + (size_t)(br * BM + wave * 8 + srow) * KDIM + scol;
        unsigned short* lA = As + wave * 512;    // + i*2048
        unsigned short* lB = Bs + wave * 512;

        // compute geometry: wave 64x64, 4x4 tiles of 16x16x32
        const int wm = (wave >> 1) * 64, wn = (wave & 1) * 64;
        const int quad = lane >> 4, mrow = lane & 15;
        const int c0 = quad ^ (mrow & 7);
        const unsigned short* aBase = As + (wm + mrow) * BK;
        const unsigned short* bBase = Bs + (wn + mrow) * BK;
        const int row0 = br * BM + wm + quad * 4;

        #pragma unroll 1
        for (int bi = 0; bi < NBC; ++bi) {
            const int bc = bcg * NBC + bi;
            const unsigned short* bStage =
                B + (size_t)(bc * BN + wave * 8 + srow) * KDIM + scol;

            f32x4 acc[4][4] = {};

            #pragma unroll 1
            for (int kt = 0; kt < KTILES; ++kt) {
                __syncthreads();   // previous tile's LDS reads done
                #pragma unroll
                for (int i = 0; i < 4; ++i) {
                    __builtin_amdgcn_global_load_lds(
                        (const __attribute__((address_space(1))) void*)(aStage + kt * BK + i * 24576),
                        (__attribute__((address_space(3))) void*)(lA + i * 2048), 16, 0, 0);
                    __builtin_amdgcn_global_load_lds(
                        (const __attribute__((address_space(1))) void*)(bStage + kt * BK + i * 24576),
                        (__attribute__((address_space(3))) void*)(lB + i * 2048), 16, 0, 0);
                }
                __syncthreads();   // staging complete

                #pragma unroll 1
                for (int ks = 0; ks < 2; ++ks) {
                    const int ck = c0 ^ (ks << 2);
                    bf16x8 af[4], bfr[4];
                    #pragma unroll
                    for (int mi = 0; mi < 4; ++mi)
                        af[mi] = *(const bf16x8*)(aBase + mi * 16 * BK + ck * 8);
                    #pragma unroll
                    for (int ni = 0; ni < 4; ++ni)
                        bfr[ni] = *(const bf16x8*)(bBase + ni * 16 * BK + ck * 8);
                    #pragma unroll
                    for (int mi = 0; mi < 4; ++mi)
                        #pragma unroll
                        for (int ni = 0; ni < 4; ++ni)
                            acc[mi][ni] = __builtin_amdgcn_mfma_f32_16x16x32_bf16(
                                af[mi], bfr[ni], acc[mi][ni], 0, 0, 0);
                }
            }

            // per-tile epilogue; C/D layout: col = lane&15, row = quad*4 + reg
            #pragma unroll
            for (int mi = 0; mi < 4; ++mi) {
                #pragma unroll
                for (int r = 0; r < 4; ++r) {
                    float v = fmaxf(fmaxf(acc[mi][0][r], acc[mi][1][r]),
                                    fmaxf(acc[mi][2][r], acc[mi][3][r]));
                    v = fmaxf(v, __shfl_xor(v, 1));
                    v = fmaxf(v, __shfl_xor(v, 2));
                    v = fmaxf(v, __shfl_xor(v, 4));
                    v = fmaxf(v, __shfl_xor(v, 8));
                    if (mrow == 0)
                        atomicMax(&out[row0 + mi * 16 + r], enc_f(v));
                }
            }
        }
    }
    grid.sync();

    // ===== phase 3: decode uint -> float in place
    {
        const int gtid = blockIdx.x * 256 + tid;
        if (gtid < NROWS) ((float*)out)[gtid] = dec_f(out[gtid]);
    }
}

// ---------------- fallback 3-kernel path (identical math, R6-proven)
__global__ __launch_bounds__(256) void normalize_cvt_k(
        const float* __restrict__ ex, const float* __restrict__ ey,
        unsigned short* __restrict__ dst, unsigned* __restrict__ out) {
    if (blockIdx.x < NROWS / 256)
        out[blockIdx.x * 256 + threadIdx.x] = enc_f(-INFINITY);
    const int wave = threadIdx.x >> 6, lane = threadIdx.x & 63;
    const int grow = blockIdx.x * 4 + wave;
    const float* src = (grow < NROWS) ? ex : ey;
    const int row = grow & (NROWS - 1);
    const float4* xr = (const float4*)(src + (size_t)row * KDIM);
    float4 v[3];
    #pragma unroll
    for (int g = 0; g < 3; ++g) v[g] = xr[lane + g * 64];
    float ss = 0.f;
    #pragma unroll
    for (int g = 0; g < 3; ++g)
        ss += v[g].x * v[g].x + v[g].y * v[g].y + v[g].z * v[g].z + v[g].w * v[g].w;
    #pragma unroll
    for (int off = 32; off > 0; off >>= 1) ss += __shfl_xor(ss, off);
    const float scale = 1.0f / fmaxf(sqrtf(ss), 1e-8f);
    ushort4* dr = (ushort4*)(dst + (size_t)grow * KDIM);
    #pragma unroll
    for (int g = 0; g < 3; ++g) {
        ushort4 o;
        o.x = f2bf_rne(v[g].x * scale); o.y = f2bf_rne(v[g].y * scale);
        o.z = f2bf_rne(v[g].z * scale); o.w = f2bf_rne(v[g].w * scale);
        dr[lane + g * 64] = o;
    }
}

__global__ __launch_bounds__(256, 4) void gemm_rowmax_k(
        const unsigned short* __restrict__ A,
        const unsigned short* __restrict__ B,
        unsigned* __restrict__ out) {
    __shared__ unsigned short As[BM * BK];
    __shared__ unsigned short Bs[BN * BK];
    const int tid  = threadIdx.x;
    const int wave = tid >> 6, lane = tid & 63;
    const int br  = blockIdx.x >> 4;
    const int bcg = blockIdx.x & 15;
    const int srow   = lane >> 3;
    const int gchunk = (lane & 7) ^ srow;
    const int scol   = gchunk * 8;
    const unsigned short* aStage = A + (size_t)(br * BM + wave * 8 + srow) * KDIM + scol;
    unsigned short* lA = As + wave * 512;
    unsigned short* lB = Bs + wave * 512;
    const int wm = (wave >> 1) * 64, wn = (wave & 1) * 64;
    const int quad = lane >> 4, mrow = lane & 15;
    const int c0 = quad ^ (mrow & 7);
    const unsigned short* aBase = As + (wm + mrow) * BK;
    const unsigned short* bBase = Bs + (wn + mrow) * BK;
    const int row0 = br * BM + wm + quad * 4;
    #pragma unroll 1
    for (int bi = 0; bi < NBC; ++bi) {
        const int bc = bcg * NBC + bi;
        const unsigned short* bStage =
            B + (size_t)(bc * BN + wave * 8 + srow) * KDIM + scol;
        f32x4 acc[4][4] = {};
        #pragma unroll 1
        for (int kt = 0; kt < KTILES; ++kt) {
            __syncthreads();
            #pragma unroll
            for (int i = 0; i < 4; ++i) {
                __builtin_amdgcn_global_load_lds(
                    (const __attribute__((address_space(1))) void*)(aStage + kt * BK + i * 24576),
                    (__attribute__((address_space(3))) void*)(lA + i * 2048), 16, 0, 0);
                __builtin_amdgcn_global_load_lds(
                    (const __attribute__((address_space(1))) void*)(bStage + kt * BK + i * 24576),
                    (__attribute__((address_space(3))) void*)(lB + i * 2048), 16, 0, 0);
            }
            __syncthreads();
            #pragma unroll 1
            for (int ks = 0; ks < 2; ++ks) {
                const int ck = c0 ^ (ks << 2);
                bf16x8 af[4], bfr[4];
                #pragma unroll
                for (int mi = 0; mi < 4; ++mi)
                    af[mi] = *(const bf16x8*)(aBase + mi * 16 * BK + ck * 8);
                #pragma unroll
                for (int ni = 0; ni < 4; ++ni)
                    bfr[ni] = *(const bf16x8*)(bBase + ni * 16 * BK + ck * 8);
                #pragma unroll
                for (int mi = 0; mi < 4; ++mi)
                    #pragma unroll
                    for (int ni = 0; ni < 4; ++ni)
                        acc[mi][ni] = __builtin_amdgcn_mfma_f32_16x16x32_bf16(
                            af[mi], bfr[ni], acc[mi][ni], 0, 0, 0);
            }
        }
        #pragma unroll
        for (int mi = 0; mi < 4; ++mi) {
            #pragma unroll
            for (int r = 0; r < 4; ++r) {
                float v = fmaxf(fmaxf(acc[mi][0][r], acc[mi][1][r]),
                                fmaxf(acc[mi][2][r], acc[mi][3][r]));
                v = fmaxf(v, __shfl_xor(v, 1));
                v = fmaxf(v, __shfl_xor(v, 2));
                v = fmaxf(v, __shfl_xor(v, 4));
                v = fmaxf(v, __shfl_xor(v, 8));
                if (mrow == 0)
                    atomicMax(&out[row0 + mi * 16 + r], enc_f(v));
            }
        }
    }
}

__global__ void decode_out_k(unsigned* __restrict__ u) {
    int i = blockIdx.x * 256 + threadIdx.x;
    ((float*)u)[i] = dec_f(u[i]);
}

extern "C" void kernel_launch(void* const* d_in, const int* in_sizes, int n_in,
                              void* d_out, int out_size, void* d_ws, size_t ws_size,
                              hipStream_t stream) {
    (void)in_sizes; (void)n_in; (void)out_size; (void)ws_size;
    const float* ex = (const float*)d_in[0];
    const float* ey = (const float*)d_in[1];
    unsigned short* wsb = (unsigned short*)d_ws;     // exn ++ eyn bf16 (25.2 MB)
    unsigned* outu = (unsigned*)d_out;

    void* args[] = {(void*)&ex, (void*)&ey, (void*)&wsb, (void*)&outu};
    hipError_t err = hipLaunchCooperativeKernel(
        (void*)fused_k, dim3((NROWS / BM) * NBCG), dim3(256), args, 0, stream);
    if (err != hipSuccess) {
        // fallback: identical math via 3-kernel chain (R6-proven)
        normalize_cvt_k<<<(2 * NROWS) / 4, 256, 0, stream>>>(ex, ey, wsb, outu);
        gemm_rowmax_k<<<(NROWS / BM) * NBCG, 256, 0, stream>>>(
            wsb, wsb + (size_t)NROWS * KDIM, outu);
        decode_out_k<<<NROWS / 256, 256, 0, stream>>>(outu);
    }
}

// Round 8
// 158.013 us; speedup vs baseline: 2.7744x; 2.7744x over previous
//
#include <hip/hip_runtime.h>
#include <math.h>

#define NROWS 8192
#define KDIM  768            // elements per row; for i8 buffers this is also BYTES
#define BM 128
#define BN 128
#define BKB 128              // K-tile bytes per row (128 i8 = 2 MFMA k-steps of 64)
#define KTILES (KDIM / BKB)  // 6
#define NBC 4                // bc tiles swept per block
#define NBCG (NROWS / BN / NBC)  // 16 -> grid 64*16 = 1024 = 4/CU

typedef int i32x4 __attribute__((ext_vector_type(4)));  // i8 MFMA A/B frag (16 bytes) and C/D

// monotonic float<->uint encoding so atomicMax(uint) == float max
static __device__ __forceinline__ unsigned enc_f(float f) {
    unsigned x = __float_as_uint(f);
    return (x & 0x80000000u) ? ~x : (x | 0x80000000u);
}
static __device__ __forceinline__ float dec_f(unsigned u) {
    unsigned x = (u & 0x80000000u) ? (u ^ 0x80000000u) : ~u;
    return __uint_as_float(x);
}

// one wave per row: fp32 normalize (exact), then symmetric int8 quantization
// with per-row scale amax/127. blocks 0..31 also init the out buffer.
__global__ __launch_bounds__(256) void normalize_quant_k(
        const float* __restrict__ ex, const float* __restrict__ ey,
        signed char* __restrict__ q, float* __restrict__ scales,
        unsigned* __restrict__ out) {
    if (blockIdx.x < NROWS / 256)
        out[blockIdx.x * 256 + threadIdx.x] = enc_f(-INFINITY);
    const int wave = threadIdx.x >> 6, lane = threadIdx.x & 63;
    const int grow = blockIdx.x * 4 + wave;          // 0..16383
    const float* src = (grow < NROWS) ? ex : ey;
    const int row = grow & (NROWS - 1);
    const float4* xr = (const float4*)(src + (size_t)row * KDIM);  // 192 float4
    float4 v[3];
    #pragma unroll
    for (int g = 0; g < 3; ++g) v[g] = xr[lane + g * 64];
    float ss = 0.f, am = 0.f;
    #pragma unroll
    for (int g = 0; g < 3; ++g) {
        ss += v[g].x * v[g].x + v[g].y * v[g].y + v[g].z * v[g].z + v[g].w * v[g].w;
        am = fmaxf(am, fmaxf(fmaxf(fabsf(v[g].x), fabsf(v[g].y)),
                             fmaxf(fabsf(v[g].z), fabsf(v[g].w))));
    }
    #pragma unroll
    for (int off = 32; off > 0; off >>= 1) {
        ss += __shfl_xor(ss, off);
        am = fmaxf(am, __shfl_xor(am, off));
    }
    const float scale = 1.0f / fmaxf(sqrtf(ss), 1e-8f);
    am = fmaxf(am * scale, 1e-12f);        // amax of the NORMALIZED row
    if (lane == 0) scales[grow] = am * (1.0f / 127.0f);
    const float si = scale * (127.0f / am);            // raw -> int8 code
    int* dr = (int*)(q + (size_t)grow * KDIM);         // 192 packed ints / row
    #pragma unroll
    for (int g = 0; g < 3; ++g) {
        int qx = min(127, max(-127, __float2int_rn(v[g].x * si)));
        int qy = min(127, max(-127, __float2int_rn(v[g].y * si)));
        int qz = min(127, max(-127, __float2int_rn(v[g].z * si)));
        int qw = min(127, max(-127, __float2int_rn(v[g].w * si)));
        dr[lane + g * 64] = (qx & 0xff) | ((qy & 0xff) << 8) |
                            ((qz & 0xff) << 16) | ((qw & 0xff) << 24);
    }
}

// A = qx i8 [8192][768B], B = qy i8 [8192][768B]; sims = (A.B^T)*sa[m]*sb[n].
// R6-proven structure, byte-identical LDS pattern (rows 128 B, 8x16B xor swizzle,
// 0 conflicts). KTILES 12->6; MFMA = i32_16x16x64_i8 (2x bf16 rate, i32 exact).
__global__ __launch_bounds__(256, 4) void gemm_rowmax_i8_k(
        const signed char* __restrict__ A, const signed char* __restrict__ B,
        const float* __restrict__ sa, const float* __restrict__ sb,
        unsigned* __restrict__ out) {
    __shared__ signed char As[BM * BKB];   // 16 KB
    __shared__ signed char Bs[BN * BKB];   // 16 KB

    const int tid  = threadIdx.x;
    const int wave = tid >> 6, lane = tid & 63;
    const int br  = blockIdx.x >> 4;       // 0..63
    const int bcg = blockIdx.x & 15;       // 0..15

    // staging: wave issue = 8 rows x 128 B; slot s of row r holds chunk s^(r&7)
    const int srow   = lane >> 3;
    const int gchunk = (lane & 7) ^ srow;
    const int scol   = gchunk * 16;        // bytes
    // issue i covers rows (wave+4i)*8+srow -> global byte offset i*24576 from base
    const signed char* aStage = A + (size_t)(br * BM + wave * 8 + srow) * KDIM + scol;
    signed char* lA = As + wave * 1024;    // + i*4096
    signed char* lB = Bs + wave * 1024;

    // compute geometry: wave 64x64, 4x4 tiles of 16x16x64
    const int wm = (wave >> 1) * 64, wn = (wave & 1) * 64;
    const int quad = lane >> 4, mrow = lane & 15;
    const int c0 = quad ^ (mrow & 7);      // swizzled chunk slot; ks=1: ^4
    const signed char* aBase = As + (wm + mrow) * BKB;
    const signed char* bBase = Bs + (wn + mrow) * BKB;
    const int row0 = br * BM + wm + quad * 4;

    #pragma unroll 1
    for (int bi = 0; bi < NBC; ++bi) {
        const int bc = bcg * NBC + bi;
        const signed char* bStage =
            B + (size_t)(bc * BN + wave * 8 + srow) * KDIM + scol;

        i32x4 acc[4][4] = {};

        #pragma unroll 1
        for (int kt = 0; kt < KTILES; ++kt) {
            __syncthreads();   // previous tile's LDS reads done
            #pragma unroll
            for (int i = 0; i < 4; ++i) {
                __builtin_amdgcn_global_load_lds(
                    (const __attribute__((address_space(1))) void*)(aStage + kt * BKB + i * 24576),
                    (__attribute__((address_space(3))) void*)(lA + i * 4096), 16, 0, 0);
                __builtin_amdgcn_global_load_lds(
                    (const __attribute__((address_space(1))) void*)(bStage + kt * BKB + i * 24576),
                    (__attribute__((address_space(3))) void*)(lB + i * 4096), 16, 0, 0);
            }
            __syncthreads();   // staging complete

            #pragma unroll 1
            for (int ks = 0; ks < 2; ++ks) {
                const int ck = c0 ^ (ks << 2);
                i32x4 af[4], bfr[4];
                #pragma unroll
                for (int mi = 0; mi < 4; ++mi)
                    af[mi] = *(const i32x4*)(aBase + mi * 16 * BKB + ck * 16);
                #pragma unroll
                for (int ni = 0; ni < 4; ++ni)
                    bfr[ni] = *(const i32x4*)(bBase + ni * 16 * BKB + ck * 16);
                #pragma unroll
                for (int mi = 0; mi < 4; ++mi)
                    #pragma unroll
                    for (int ni = 0; ni < 4; ++ni)
                        acc[mi][ni] = __builtin_amdgcn_mfma_i32_16x16x64_i8(
                            af[mi], bfr[ni], acc[mi][ni], 0, 0, 0);
            }
        }

        // epilogue: fold sb[col] per ni (col = lane&15 within each 16-tile),
        // in-lane ni max, shfl-max over 16 cols, then *sa[row] (sa>0 commutes).
        // C/D layout: col = lane&15, row = quad*4 + reg (dtype-independent).
        float sbv[4];
        #pragma unroll
        for (int ni = 0; ni < 4; ++ni)
            sbv[ni] = sb[bc * BN + wn + ni * 16 + mrow];
        #pragma unroll
        for (int mi = 0; mi < 4; ++mi) {
            #pragma unroll
            for (int r = 0; r < 4; ++r) {
                float v = fmaxf(fmaxf((float)acc[mi][0][r] * sbv[0],
                                      (float)acc[mi][1][r] * sbv[1]),
                                fmaxf((float)acc[mi][2][r] * sbv[2],
                                      (float)acc[mi][3][r] * sbv[3]));
                v = fmaxf(v, __shfl_xor(v, 1));
                v = fmaxf(v, __shfl_xor(v, 2));
                v = fmaxf(v, __shfl_xor(v, 4));
                v = fmaxf(v, __shfl_xor(v, 8));
                if (mrow == 0) {
                    const int row = row0 + mi * 16 + r;
                    atomicMax(&out[row], enc_f(v * sa[row]));
                }
            }
        }
    }
}

__global__ void decode_out_k(unsigned* __restrict__ u) {
    int i = blockIdx.x * 256 + threadIdx.x;
    ((float*)u)[i] = dec_f(u[i]);
}

extern "C" void kernel_launch(void* const* d_in, const int* in_sizes, int n_in,
                              void* d_out, int out_size, void* d_ws, size_t ws_size,
                              hipStream_t stream) {
    (void)in_sizes; (void)n_in; (void)out_size; (void)ws_size;
    const float* ex = (const float*)d_in[0];
    const float* ey = (const float*)d_in[1];
    // ws layout: qx[8192*768 B] ++ qy[8192*768 B] ++ scales[16384 f32]  (~12.6 MB)
    signed char* q = (signed char*)d_ws;
    float* scales  = (float*)(q + 2 * (size_t)NROWS * KDIM);
    unsigned* outu = (unsigned*)d_out;

    normalize_quant_k<<<(2 * NROWS) / 4, 256, 0, stream>>>(ex, ey, q, scales, outu);
    gemm_rowmax_i8_k<<<(NROWS / BM) * NBCG, 256, 0, stream>>>(
        q, q + (size_t)NROWS * KDIM, scales, scales + NROWS, outu);
    decode_out_k<<<NROWS / 256, 256, 0, stream>>>(outu);
}